// Round 3
// baseline (550.286 us; speedup 1.0000x reference)
//
#include <hip/hip_runtime.h>

// TT-layer y = (c0 x c1 x c2 x c3) . x + bias, B=8192, dims 8, ranks 16.
// Precompute (tt_pre, into d_ws, fp32->bf16):
//   CC [n1][q=(n2*16+r2)][p=(m1*8+m2)] = sum_r1 c0*c1   (8x128x64)
//   C23[row=(n3*8+n4)][s~(r2,m3,m4)]   = sum_r3 c2*c3   (64x1024, s swizzled)
// tt_main: 2 batch/block, per n1: stage01 GEMM (128x128x64) -> scatter bf16 ->
// t2t (double-buffered, ONE barrier/n1) -> stage2 GEMM (64x16x1024) -> out.
// Registers: a2 (C23 frags) = 128 VGPR/wave is structural -> 2 waves/SIMD;
// this version attacks latency via dbuf (-8 barriers/block), 4 indep stage2
// chains, and packed bf16 converts.

typedef __attribute__((ext_vector_type(8))) short bf16x8;
typedef __attribute__((ext_vector_type(4))) float f32x4;

__device__ __forceinline__ short f2bf(float f) {
    union { float f; unsigned u; } v; v.f = f;
    unsigned u = v.u;
    u += 0x7fffu + ((u >> 16) & 1u);   // round-to-nearest-even
    return (short)(u >> 16);
}

__device__ __forceinline__ int pk_bf16(float a, float b) {
#if __has_builtin(__builtin_amdgcn_cvt_pk_bf16_f32)
    typedef __attribute__((ext_vector_type(2))) __bf16 bf16x2_t;
    union { bf16x2_t v; int i; } u;
    u.v = __builtin_amdgcn_cvt_pk_bf16_f32(a, b);
    return u.i;
#else
    return (int)((unsigned short)f2bf(a) | ((unsigned)(unsigned short)f2bf(b) << 16));
#endif
}

// ---------------- precompute kernel ----------------
__global__ void tt_pre(const float* __restrict__ c0, const float* __restrict__ c1,
                       const float* __restrict__ c2, const float* __restrict__ c3,
                       short* __restrict__ ws) {
    int id = blockIdx.x * 256 + threadIdx.x;     // 0 .. 131071
    if (id < 65536) {
        int p  = id & 63, q = (id >> 6) & 127, n1 = id >> 13;
        int m1 = p >> 3, m2 = p & 7, n2 = q >> 4, r2 = q & 15;
        float s = 0.f;
        #pragma unroll
        for (int r1 = 0; r1 < 16; ++r1)
            s += c0[(n1 * 8 + m1) * 16 + r1] * c1[((r1 * 8 + n2) * 8 + m2) * 16 + r2];
        ws[id] = f2bf(s);
    } else {
        int id2 = id - 65536;
        int s_  = id2 & 1023, row = id2 >> 10;
        int n3 = row >> 3, n4 = row & 7;
        int m3 = s_ >> 7, m4 = (s_ >> 4) & 7, r2s = s_ & 15;
        int r2 = (r2s - 4 * (m3 & 1)) & 15;      // inverse scatter swizzle
        float s = 0.f;
        #pragma unroll
        for (int r3 = 0; r3 < 16; ++r3)
            s += c2[((r2 * 8 + n3) * 8 + m3) * 16 + r3] * c3[(r3 * 8 + n4) * 8 + m4];
        ws[65536 + id2] = f2bf(s);
    }
}

// ---------------- main kernel ----------------
#define XT_S 72      // xt row stride (shorts)
#define T2_S 1032    // t2t row stride (shorts)
#define T2_HALF 16512  // shorts per t2t buffer (16 * T2_S)

__global__ __launch_bounds__(256, 2) void tt_main(
    const float* __restrict__ x, const short* __restrict__ ws,
    const float* __restrict__ bias, float* __restrict__ out)
{
    __shared__ short lds[2 * T2_HALF];   // t2t double buffer; xt overlays [0,9216)

    const short* cc  = ws;               // [8][128][64]
    const short* c23 = ws + 65536;       // [64][1024]

    const int t = threadIdx.x, w = t >> 6, L = t & 63;
    const int quad = L >> 4, l16 = L & 15;
    const long long b0 = (long long)blockIdx.x * 2;

    // ---- build xt bf16 transposed: xt[(b'*64+u)][p], wave w -> b'=w>>1, p-half w&1
    {
        const float* xb = x + (b0 + (w >> 1)) * 4096;
        const int pr = (w & 1) * 32;
        short* dst = &lds[(((w >> 1) * 64 + L) * XT_S) + pr];
        #pragma unroll
        for (int g = 0; g < 4; ++g) {
            float v[8];
            #pragma unroll
            for (int j = 0; j < 8; ++j) v[j] = xb[(pr + g * 8 + j) * 64 + L];
            int4 pk;
            pk.x = pk_bf16(v[0], v[1]); pk.y = pk_bf16(v[2], v[3]);
            pk.z = pk_bf16(v[4], v[5]); pk.w = pk_bf16(v[6], v[7]);
            *(int4*)(dst + g * 8) = pk;
        }
    }

    // ---- persistent A2 frags (C23): wave w -> rows 16w..16w+15, full K=1024
    bf16x8 a2[32];
    {
        const short* base = c23 + (16 * w + l16) * 1024 + quad * 8;
        #pragma unroll
        for (int kt = 0; kt < 32; ++kt) a2[kt] = *(const bf16x8*)(base + kt * 32);
    }
    __syncthreads();                     // xt visible to all waves

    // ---- persistent B01 frags (x): wave -> (mh, nh); nh picks b'
    const int mh = w >> 1, nh = w & 1;
    bf16x8 b01[8];                       // [kt*4+nt]
    #pragma unroll
    for (int kt = 0; kt < 2; ++kt)
        #pragma unroll
        for (int nt = 0; nt < 4; ++nt)
            b01[kt * 4 + nt] =
                *(const bf16x8*)&lds[(nh * 64 + nt * 16 + l16) * XT_S + kt * 32 + quad * 8];
    __syncthreads();                     // all xt reads done before scatter overwrites

    #pragma unroll 1
    for (int n1 = 0; n1 < 8; ++n1) {
        short* t2t = lds + (n1 & 1) * T2_HALF;

        // ======== stage01 in two nt-passes (acc footprint 32 regs) ========
        #pragma unroll
        for (int half = 0; half < 2; ++half) {
            f32x4 acc[4][2] = {};        // [mt][nt-within-half]
            #pragma unroll
            for (int kt = 0; kt < 2; ++kt) {
                bf16x8 a1[4];
                const short* ab = cc + n1 * 8192 + (mh * 64 + l16) * 64 + kt * 32 + quad * 8;
                #pragma unroll
                for (int mt = 0; mt < 4; ++mt) a1[mt] = *(const bf16x8*)(ab + mt * 16 * 64);
                #pragma unroll
                for (int mt = 0; mt < 4; ++mt)
                    #pragma unroll
                    for (int nj = 0; nj < 2; ++nj)
                        acc[mt][nj] = __builtin_amdgcn_mfma_f32_16x16x32_bf16(
                            a1[mt], b01[kt * 4 + half * 2 + nj], acc[mt][nj], 0, 0, 0);
            }
            // ---- scatter this half -> t2t (b64 stores, swizzled s)
            #pragma unroll
            for (int mt = 0; mt < 4; ++mt) {
                const int n2 = mh * 4 + mt;
                #pragma unroll
                for (int nj = 0; nj < 2; ++nj) {
                    const int nt = half * 2 + nj;
                    const int u  = nt * 16 + l16;
                    const int m3 = u >> 3, m4 = u & 7;
                    const int rblk = (quad * 4 + 4 * (m3 & 1)) & 15;
                    int2 pk;
                    pk.x = pk_bf16(acc[mt][nj][0], acc[mt][nj][1]);
                    pk.y = pk_bf16(acc[mt][nj][2], acc[mt][nj][3]);
                    *(int2*)&t2t[(nh * 8 + n2) * T2_S + (m3 * 8 + m4) * 16 + rblk] = pk;
                }
            }
        }
        __syncthreads();                 // t2t[p] complete (the ONLY barrier per n1)

        // ======== stage2: y = C23 * t2t, M=64 N=16 K=1024, 4 indep chains ====
        f32x4 d0 = {}, d1 = {}, d2 = {}, d3 = {};
        {
            const short* tb = &t2t[l16 * T2_S + quad * 8];
            #pragma unroll
            for (int kt = 0; kt < 32; kt += 4) {
                bf16x8 bf0 = *(const bf16x8*)(tb + kt * 32);
                bf16x8 bf1 = *(const bf16x8*)(tb + kt * 32 + 32);
                bf16x8 bf2 = *(const bf16x8*)(tb + kt * 32 + 64);
                bf16x8 bf3 = *(const bf16x8*)(tb + kt * 32 + 96);
                d0 = __builtin_amdgcn_mfma_f32_16x16x32_bf16(a2[kt],     bf0, d0, 0, 0, 0);
                d1 = __builtin_amdgcn_mfma_f32_16x16x32_bf16(a2[kt + 1], bf1, d1, 0, 0, 0);
                d2 = __builtin_amdgcn_mfma_f32_16x16x32_bf16(a2[kt + 2], bf2, d2, 0, 0, 0);
                d3 = __builtin_amdgcn_mfma_f32_16x16x32_bf16(a2[kt + 3], bf3, d3, 0, 0, 0);
            }
        }
        // ---- epilogue: rows 16w+quad*4+i, col l16=(b',n2)
        {
            const int bp = l16 >> 3, n2 = l16 & 7;
            const int off = n1 * 512 + n2 * 64 + 16 * w + quad * 4;
            const float4 bv = *(const float4*)(bias + off);
            float4 ov;
            ov.x = d0[0] + d1[0] + d2[0] + d3[0] + bv.x;
            ov.y = d0[1] + d1[1] + d2[1] + d3[1] + bv.y;
            ov.z = d0[2] + d1[2] + d2[2] + d3[2] + bv.z;
            ov.w = d0[3] + d1[3] + d2[3] + d3[3] + bv.w;
            *(float4*)(out + (b0 + bp) * 4096 + off) = ov;
        }
        // no trailing barrier: next n1 scatters into the other t2t buffer;
        // the n1+1 mid-loop barrier (lgkmcnt(0) drain) orders reads of this
        // buffer before the n1+2 scatter reuses it.
    }
}

extern "C" void kernel_launch(void* const* d_in, const int* in_sizes, int n_in,
                              void* d_out, int out_size, void* d_ws, size_t ws_size,
                              hipStream_t stream) {
    const float* x    = (const float*)d_in[0];
    const float* c0   = (const float*)d_in[1];
    const float* c1   = (const float*)d_in[2];
    const float* c2   = (const float*)d_in[3];
    const float* c3   = (const float*)d_in[4];
    const float* bias = (const float*)d_in[5];
    float* out = (float*)d_out;
    short* ws  = (short*)d_ws;           // 256 KB used: CC (128K) + C23 (128K)

    hipLaunchKernelGGL(tt_pre, dim3(512), dim3(256), 0, stream, c0, c1, c2, c3, ws);
    hipLaunchKernelGGL(tt_main, dim3(4096), dim3(256), 0, stream, x, ws, bias, out);
}